// Round 4
// baseline (29.714 us; speedup 1.0000x reference)
//
#include <hip/hip_runtime.h>

// Problem dims (fixed by reference setup_inputs)
constexpr int B = 4, P = 8, H = 32, W = 32, D = 32, C = 16;

using f32x4 = __attribute__((ext_vector_type(4))) float;

__global__ __launch_bounds__(256) void resample3d_kernel(
    const float* __restrict__ fmap,   // [B,P,H,W,D,C]
    const float* __restrict__ theta,  // [B,P,3,4]
    float* __restrict__ out)          // [B,P,H,W,D,C]
{
    // 8 lanes per voxel: lane = (zbit, chunk). Each thread loads the 4
    // (y,x)-corner chunks for its (zbit, chunk); an 8-lane group's load is a
    // contiguous 128 B line (z0 chunk0..3, z1 chunk0..3) -> half the TA line
    // requests of the scattered 64 B layout.
    //
    // XCD swizzle: 32768 blocks = 32 bp-slices x 1024 blocks. Dispatch is
    // round-robin over 8 XCDs; remap so each XCD walks consecutive blocks of
    // the same bp slice (2 MB, fits the 4 MiB per-XCD L2).
    const int orig = blockIdx.x;
    const int virt = (orig & 7) * 4096 + (orig >> 3);   // bijective

    const int tid  = threadIdx.x;
    const int zbit = (tid >> 2) & 1;
    const int chunk = tid & 3;
    const int vox = virt * 32 + (tid >> 3);  // 32 voxels per block
    const int k   =  vox        & (D - 1);
    const int j   = (vox >> 5)  & (W - 1);
    const int i   = (vox >> 10) & (H - 1);
    const int bp  = virt >> 10;              // block-uniform

    // theta row-major [3][4]; bp block-uniform -> scalar loads
    const float4* th4 = (const float4*)(theta + bp * 12);
    const float4 t0 = th4[0];   // -> y_s
    const float4 t1 = th4[1];   // -> x_s
    const float4 t2 = th4[2];   // -> z_s

    const float fi = (float)i, fj = (float)j, fk = (float)k;
    const float y = fmaf(t0.x, fi, fmaf(t0.y, fj, fmaf(t0.z, fk, t0.w))) + 2.0f;
    const float x = fmaf(t1.x, fi, fmaf(t1.y, fj, fmaf(t1.z, fk, t1.w))) + 2.0f;
    const float z = fmaf(t2.x, fi, fmaf(t2.y, fj, fmaf(t2.z, fk, t2.w))) + 2.0f;

    // ref: ?0 = clip(floor(?), 0, 34); ?d = ? - ?0 (NOT re-clamped)
    const float fy0 = fminf(fmaxf(floorf(y), 0.0f), 34.0f);
    const float fx0 = fminf(fmaxf(floorf(x), 0.0f), 34.0f);
    const float fz0 = fminf(fmaxf(floorf(z), 0.0f), 34.0f);
    const float yd = y - fy0, xd = x - fx0, zd = z - fz0;
    const int ty0 = (int)fy0 - 2, tx0 = (int)fx0 - 2, tz0 = (int)fz0 - 2;

    // Branchless pad handling: OOB tap gets weight 0 + clamped-safe address.
    float wy[2], wx[2];
    int   iy[2], ix[2];
    wy[0] = ((unsigned)ty0       < (unsigned)H) ? (1.0f - yd) : 0.0f;
    wy[1] = ((unsigned)(ty0 + 1) < (unsigned)H) ? yd          : 0.0f;
    wx[0] = ((unsigned)tx0       < (unsigned)W) ? (1.0f - xd) : 0.0f;
    wx[1] = ((unsigned)(tx0 + 1) < (unsigned)W) ? xd          : 0.0f;
    iy[0] = min(max(ty0, 0), H - 1);  iy[1] = min(max(ty0 + 1, 0), H - 1);
    ix[0] = min(max(tx0, 0), W - 1);  ix[1] = min(max(tx0 + 1, 0), W - 1);

    // This lane's z tap:
    const int tz = tz0 + zbit;
    const float wzl = ((unsigned)tz < (unsigned)D)
                        ? (zbit ? zd : (1.0f - zd)) : 0.0f;
    const int izl = min(max(tz, 0), D - 1);

    const float* base = fmap + bp * (H * W * D * C) + izl * C + chunk * 4;

    // Issue all 4 line-loads, then blend.
    f32x4 v[4];
    float w[4];
    #pragma unroll
    for (int a = 0; a < 2; ++a)
        #pragma unroll
        for (int b2 = 0; b2 < 2; ++b2) {
            const int cn = a * 2 + b2;
            w[cn] = wy[a] * wx[b2] * wzl;
            v[cn] = *(const f32x4*)(base + iy[a] * (W * D * C) + ix[b2] * (D * C));
        }

    f32x4 acc = {0.f, 0.f, 0.f, 0.f};
    #pragma unroll
    for (int cn = 0; cn < 4; ++cn)
        acc += w[cn] * v[cn];

    // Reduce z0+z1 partials across the 8-lane group (lane ^ 4).
    #pragma unroll
    for (int r = 0; r < 4; ++r)
        acc[r] += __shfl_xor(acc[r], 4);

    // zbit==0 lanes hold the final chunk; 4 lanes x 16 B = voxel's 64 B.
    if (!zbit) {
        float* outp = out + (size_t)vox * C + chunk * 4;
        __builtin_nontemporal_store(acc, (f32x4*)outp);
    }
}

extern "C" void kernel_launch(void* const* d_in, const int* in_sizes, int n_in,
                              void* d_out, int out_size, void* d_ws, size_t ws_size,
                              hipStream_t stream) {
    const float* fmap  = (const float*)d_in[0];
    const float* theta = (const float*)d_in[1];
    float* out = (float*)d_out;

    const int total_threads = B * P * H * W * D * 8;   // 8 lanes per voxel
    const int block = 256;
    const int grid = total_threads / block;            // 32768
    resample3d_kernel<<<grid, block, 0, stream>>>(fmap, theta, out);
}

// Round 5
// 28.952 us; speedup vs baseline: 1.0263x; 1.0263x over previous
//
#include <hip/hip_runtime.h>

// Problem dims (fixed by reference setup_inputs)
constexpr int B = 4, P = 8, H = 32, W = 32, D = 32, C = 16;

using f32x4 = __attribute__((ext_vector_type(4))) float;

__global__ __launch_bounds__(256) void resample3d_kernel(
    const float* __restrict__ fmap,   // [B,P,H,W,D,C]
    const float* __restrict__ theta,  // [B,P,3,4]
    float* __restrict__ out)          // [B,P,H,W,D,C]
{
    // Layout: 8 lanes per voxel (zbit,chunk) -> each gather group is a
    // contiguous 128 B line. Each thread serves a CONSECUTIVE k-pair
    // (k0, k0+1): halves wave count vs round 4 (VALU per voxel back to
    // round-3 level) and overlaps the pair's z-windows in L1.
    // Block = (bp, i, 2 j-rows, all 32 k) = 64 voxels; y/x corner lines are
    // reused across the block's two j-rows and consecutive k (L1 locality).
    //
    // Grid 16384 = 32 bp-slices x 512. XCD swizzle (bijective, nwg%8==0):
    // each XCD walks consecutive blocks of ~4 bp slices (L2 locality).
    const int orig = blockIdx.x;
    const int virt = (orig & 7) * 2048 + (orig >> 3);
    const int bp = virt >> 9;                 // block-uniform
    const int blk = virt & 511;
    const int i   = blk >> 4;

    const int tid   = threadIdx.x;
    const int chunk = tid & 3;                // float4 chunk of C=16
    const int zbit  = (tid >> 2) & 1;         // z0 / z1 tap
    const int kb    = (tid >> 3) & 15;        // k-pair index
    const int dj    = tid >> 7;
    const int j  = ((blk & 15) << 1) | dj;
    const int k0 = kb << 1;                   // voxels k0, k0+1

    // theta row-major [3][4]; bp block-uniform -> scalar loads
    const float4* th4 = (const float4*)(theta + bp * 12);
    const float4 t0 = th4[0];   // -> y_s
    const float4 t1 = th4[1];   // -> x_s
    const float4 t2 = th4[2];   // -> z_s

    const float fi = (float)i, fj = (float)j, fk = (float)k0;
    float yc[2], xc[2], zc[2];
    yc[0] = fmaf(t0.x, fi, fmaf(t0.y, fj, fmaf(t0.z, fk, t0.w))) + 2.0f;
    xc[0] = fmaf(t1.x, fi, fmaf(t1.y, fj, fmaf(t1.z, fk, t1.w))) + 2.0f;
    zc[0] = fmaf(t2.x, fi, fmaf(t2.y, fj, fmaf(t2.z, fk, t2.w))) + 2.0f;
    yc[1] = yc[0] + t0.z;                     // k0+1
    xc[1] = xc[0] + t1.z;
    zc[1] = zc[0] + t2.z;

    const float* fbase = fmap + bp * (H * W * D * C) + chunk * 4;

    // Per-voxel: 4 (y,x)-corner offsets + weights for this lane's z tap.
    // Branchless pad handling: OOB tap -> weight 0, clamped-safe address.
    int   off[2][4];
    float wgt[2][4];
    #pragma unroll
    for (int v = 0; v < 2; ++v) {
        const float y = yc[v], x = xc[v], z = zc[v];
        const float fy0 = fminf(fmaxf(floorf(y), 0.0f), 34.0f);
        const float fx0 = fminf(fmaxf(floorf(x), 0.0f), 34.0f);
        const float fz0 = fminf(fmaxf(floorf(z), 0.0f), 34.0f);
        const float yd = y - fy0, xd = x - fx0, zd = z - fz0;
        const int ty0 = (int)fy0 - 2, tx0 = (int)fx0 - 2, tz0 = (int)fz0 - 2;

        float wy[2], wx[2];
        int   iy[2], ix[2];
        wy[0] = ((unsigned)ty0       < (unsigned)H) ? (1.0f - yd) : 0.0f;
        wy[1] = ((unsigned)(ty0 + 1) < (unsigned)H) ? yd          : 0.0f;
        wx[0] = ((unsigned)tx0       < (unsigned)W) ? (1.0f - xd) : 0.0f;
        wx[1] = ((unsigned)(tx0 + 1) < (unsigned)W) ? xd          : 0.0f;
        iy[0] = min(max(ty0, 0), H - 1);  iy[1] = min(max(ty0 + 1, 0), H - 1);
        ix[0] = min(max(tx0, 0), W - 1);  ix[1] = min(max(tx0 + 1, 0), W - 1);

        const int tz = tz0 + zbit;
        const float wzl = ((unsigned)tz < (unsigned)D)
                            ? (zbit ? zd : (1.0f - zd)) : 0.0f;
        const int izl = min(max(tz, 0), D - 1);

        #pragma unroll
        for (int a = 0; a < 2; ++a)
            #pragma unroll
            for (int b2 = 0; b2 < 2; ++b2) {
                const int cn = a * 2 + b2;
                off[v][cn] = iy[a] * (W * D * C) + ix[b2] * (D * C) + izl * C;
                wgt[v][cn] = wy[a] * wx[b2] * wzl;
            }
    }

    // Issue all 8 line-group loads, then blend.
    f32x4 val[2][4];
    #pragma unroll
    for (int cn = 0; cn < 4; ++cn) {
        val[0][cn] = *(const f32x4*)(fbase + off[0][cn]);
        val[1][cn] = *(const f32x4*)(fbase + off[1][cn]);
    }

    f32x4 acc0 = {0.f, 0.f, 0.f, 0.f};
    f32x4 acc1 = {0.f, 0.f, 0.f, 0.f};
    #pragma unroll
    for (int cn = 0; cn < 4; ++cn) {
        acc0 += wgt[0][cn] * val[0][cn];
        acc1 += wgt[1][cn] * val[1][cn];
    }

    // Reduce z0+z1 partials across the 8-lane group (lane ^ 4).
    #pragma unroll
    for (int r = 0; r < 4; ++r) {
        acc0[r] += __shfl_xor(acc0[r], 4);
        acc1[r] += __shfl_xor(acc1[r], 4);
    }

    // zbit==0 lanes store both voxels (write-once -> non-temporal).
    if (!zbit) {
        float* outp = out + bp * (H * W * D * C)
                          + ((i * W + j) * D + k0) * C + chunk * 4;
        __builtin_nontemporal_store(acc0, (f32x4*)outp);
        __builtin_nontemporal_store(acc1, (f32x4*)(outp + C));
    }
}

extern "C" void kernel_launch(void* const* d_in, const int* in_sizes, int n_in,
                              void* d_out, int out_size, void* d_ws, size_t ws_size,
                              hipStream_t stream) {
    const float* fmap  = (const float*)d_in[0];
    const float* theta = (const float*)d_in[1];
    float* out = (float*)d_out;

    // 8 lanes/voxel, 2 voxels/thread: B*P*H*W*D*8/2 threads
    const int total_threads = B * P * H * W * D * 4;
    const int block = 256;
    const int grid = total_threads / block;            // 16384
    resample3d_kernel<<<grid, block, 0, stream>>>(fmap, theta, out);
}